// Round 5
// baseline (20.889 us; speedup 1.0000x reference)
//
#include <hip/hip_runtime.h>
#include <hip/hip_bf16.h>

// LearnableInterpolation: out[b,t,n] = sum_o softmax_o(-3*(tpos[o,n]-tgt[t])^2) * x[b,o,n]
// B=32, L_org=L_to=2048, N=21. Softmax over o is a near-delta -> 17-tap window.
//
// R5: R4's interp structure (weights amortized in registers over batches,
// 4 outputs/thread) but gather reads from TRANSPOSED xt[N,B,L] so each
// (n,b) window is 107 CONTIGUOUS floats (7 cache lines) instead of 107
// stride-84B lines. Gather transactions: 2.3M -> 0.15M lines.
// k1 = tiled transpose (coalesced both sides, ~11MB through L2/L3).

constexpr int LORG  = 2048;
constexpr int LTO   = 2048;
constexpr int NCH   = 21;
constexpr int BATCH = 32;
constexpr int W     = 8;
constexpr int NW    = 2 * W + 1;   // 17 taps
constexpr int TT    = 64;          // t-tile
constexpr int BH    = 16;          // batches per block
constexpr int XSTR  = 108;         // window len <= ceil(63/0.7)+17 = 107

constexpr float MIN_RATIO = 0.7f, MAX_RATIO = 1.3f;
constexpr float MIN_BIAS  = -4.0f, MAX_BIAS = 4.0f;
constexpr float NEG3LOG2E = -3.0f * 1.4426950408889634f;  // log2-domain scale

__device__ __forceinline__ int compute_o0(float tg, float bb, float ir) {
    const float ocf = (float)LORG + (tg - bb) * ir;
    int o0 = (int)floorf(ocf + 0.5f) - W;
    return max(0, min(LORG - NW, o0));
}

// ---------------- kernel 1: transpose x[B,LORG,NCH] -> xt[NCH,BATCH,LORG] ---
__global__ __launch_bounds__(256) void li_transpose(
    const float* __restrict__ x, float* __restrict__ xt)
{
    const int b  = blockIdx.y;
    const int o0 = blockIdx.x * 64;
    __shared__ float tile[64 * NCH];
    const float* src = x + ((size_t)b * LORG + o0) * NCH;
    for (int i = threadIdx.x; i < 64 * NCH; i += 256) tile[i] = src[i];
    __syncthreads();
    for (int j = threadIdx.x; j < 64 * NCH; j += 256) {
        const int n = j >> 6, k = j & 63;              // lane==k -> coalesced write
        xt[((size_t)(n * BATCH + b)) * LORG + o0 + k] = tile[k * NCH + n];
    }
}

// ---------------- kernel 2: interpolation from xt ---------------------------
__global__ __launch_bounds__(256) void li_interp(
    const float* __restrict__ xt,     // [NCH, BATCH, LORG]
    const float* __restrict__ rmo,
    const float* __restrict__ bias,
    float* __restrict__ out)          // [B, LTO, NCH]
{
    const int t0 = blockIdx.x * TT;
    const int b0 = blockIdx.y * BH;
    const int n  = blockIdx.z;

    const int tid = threadIdx.x;
    const int tl  = tid & 63;              // this thread's t within the tile
    const int bg  = tid >> 6;              // wave id 0..3 -> batch group

    __shared__ float xs[BH][XSTR];

    const float r  = fminf(fmaxf(rmo[n] + 1.0f, MIN_RATIO), MAX_RATIO);
    const float bb = fminf(fmaxf(bias[n], MIN_BIAS), MAX_BIAS);
    const float ir = 1.0f / r;

    // block-wide window (o0 monotone in t)
    const int lo  = compute_o0((float)(t0 - LTO), bb, ir);
    const int hi  = compute_o0((float)(t0 + TT - 1 - LTO), bb, ir);
    const int len = hi + NW - lo;          // <= 107

    // ---- per-thread weights for its tl (registers; amortized over b) ----
    const float tg = (float)(t0 + tl - LTO);
    const int   o0 = compute_o0(tg, bb, ir);
    const int base = o0 - lo;
    float d = (float)(o0 - LORG) * r + bb - tg;      // d_j = d + j*r
    // analytic max of -3*d_j^2 over j in [0,16]: nearest j to -d/r
    float js = floorf(-d * ir + 0.5f);
    js = fminf(fmaxf(js, 0.0f), 16.0f);
    const float dstar = d + js * r;
    const float m = NEG3LOG2E * dstar * dstar;       // log2-domain max
    float w[NW];
    float s = 0.0f;
    #pragma unroll
    for (int j = 0; j < NW; ++j) {
        const float e = NEG3LOG2E * d * d - m;       // <= 0
        w[j] = exp2f(e);                             // native v_exp_f32
        s += w[j];
        d += r;
    }
    const float inv = 1.0f / s;                      // s >= 1, no NaN

    // ---- stage 16 contiguous windows from xt (coalesced) ----
    const float* colbase = xt + ((size_t)n * BATCH + b0) * LORG + lo;
    for (int idx = tid; idx < BH * 128; idx += 256) {
        const int bl = idx >> 7, i = idx & 127;
        if (i < len) xs[bl][i] = colbase[(size_t)bl * LORG + i];
    }
    __syncthreads();

    // ---- compute: 4 outputs per thread (fixed tl, 4 batches) ----
    for (int bl = bg; bl < BH; bl += 4) {
        float acc = 0.0f;
        #pragma unroll
        for (int j = 0; j < NW; ++j)
            acc = fmaf(w[j], xs[bl][base + j], acc);
        out[((size_t)(b0 + bl) * LTO + t0 + tl) * NCH + n] = acc * inv;
    }
}

// ---------------- fallback (R4 fused kernel) if ws too small ----------------
__global__ __launch_bounds__(256) void li_fused(
    const float* __restrict__ x,
    const float* __restrict__ rmo,
    const float* __restrict__ bias,
    float* __restrict__ out)
{
    const int h   = blockIdx.x;
    const int NB  = NCH * (LTO / TT) * (BATCH / BH);
    const int wk  = (h & 7) * (NB / 8) + (h >> 3);
    const int bh  = wk & 1;
    const int tn  = wk >> 1;
    const int tt  = tn / NCH;
    const int n   = tn - tt * NCH;
    const int t0  = tt * TT;
    const int tid = threadIdx.x;
    const int tl  = tid & 63;
    const int wv  = tid >> 6;
    const int b0  = bh * BH;

    __shared__ float xs[BH][113];

    const float r  = fminf(fmaxf(rmo[n] + 1.0f, MIN_RATIO), MAX_RATIO);
    const float bb = fminf(fmaxf(bias[n], MIN_BIAS), MAX_BIAS);
    const float ir = 1.0f / r;
    const int lo  = compute_o0((float)(t0 - LTO), bb, ir);
    const int hi  = compute_o0((float)(t0 + TT - 1 - LTO), bb, ir);
    const int len = hi + NW - lo;

    const float tg = (float)(t0 + tl - LTO);
    const int   o0 = compute_o0(tg, bb, ir);
    const int base = o0 - lo;
    float d = (float)(o0 - LORG) * r + bb - tg;
    float js = floorf(-d * ir + 0.5f);
    js = fminf(fmaxf(js, 0.0f), 16.0f);
    const float dstar = d + js * r;
    const float m = NEG3LOG2E * dstar * dstar;
    float w[NW];
    float s = 0.0f;
    #pragma unroll
    for (int j = 0; j < NW; ++j) {
        const float e = NEG3LOG2E * d * d - m;
        w[j] = exp2f(e);
        s += w[j];
        d += r;
    }
    const float inv = 1.0f / s;

    for (int bl = wv; bl < BH; bl += 4) {
        const float* col = x + ((size_t)((b0 + bl) * LORG + lo)) * NCH + n;
        for (int i = tl; i < len; i += 64)
            xs[bl][i] = col[(size_t)i * NCH];
    }
    __syncthreads();

    for (int bl = wv; bl < BH; bl += 4) {
        float acc = 0.0f;
        #pragma unroll
        for (int j = 0; j < NW; ++j)
            acc = fmaf(w[j], xs[bl][base + j], acc);
        out[((size_t)(b0 + bl) * LTO + t0 + tl) * NCH + n] = acc * inv;
    }
}

extern "C" void kernel_launch(void* const* d_in, const int* in_sizes, int n_in,
                              void* d_out, int out_size, void* d_ws, size_t ws_size,
                              hipStream_t stream) {
    const float* x    = (const float*)d_in[0];
    const float* rmo  = (const float*)d_in[1];
    const float* bias = (const float*)d_in[2];
    float* out = (float*)d_out;

    const size_t xt_bytes = (size_t)NCH * BATCH * LORG * sizeof(float);
    if (ws_size >= xt_bytes) {
        float* xt = (float*)d_ws;
        li_transpose<<<dim3(LORG / 64, BATCH), 256, 0, stream>>>(x, xt);
        li_interp<<<dim3(LTO / TT, BATCH / BH, NCH), 256, 0, stream>>>(xt, rmo, bias, out);
    } else {
        const int NB = NCH * (LTO / TT) * (BATCH / BH);
        li_fused<<<NB, 256, 0, stream>>>(x, rmo, bias, out);
    }
}

// Round 6
// 16.847 us; speedup vs baseline: 1.2399x; 1.2399x over previous
//
#include <hip/hip_runtime.h>
#include <hip/hip_bf16.h>

// LearnableInterpolation: out[b,t,n] = sum_o softmax_o(-3*(tpos[o,n]-tgt[t])^2) * x[b,o,n]
// B=32, L_org=L_to=2048, N=21. Softmax over o is a near-delta -> 17-tap window.
//
// R6: R4's fused single kernel (weights amortized in registers over batches),
// but BARRIER-FREE: LDS is per-wave (xs[wave][2][128]); wave wv owns batches
// {wv, wv+4, wv+8, wv+12} end-to-end, so no __syncthreads is needed (the
// compiler inserts the wave-internal lgkmcnt wait for the aliasing LDS
// accesses). Staging is double-buffered with issue-early loads: next batch's
// 2 global loads are issued BEFORE computing the current batch, hiding L2/HBM
// latency under 17 FMA + LDS reads + store (T14-lite). k-loop fully unrolled
// so LDS buffer indices are compile-time constants.

constexpr int LORG  = 2048;
constexpr int LTO   = 2048;
constexpr int NCH   = 21;
constexpr int BATCH = 32;
constexpr int W     = 8;
constexpr int NW    = 2 * W + 1;   // 17 taps
constexpr int TT    = 64;          // t-tile
constexpr int BH    = 16;          // batches per block
constexpr int NBLK  = NCH * (LTO / TT) * (BATCH / BH);   // 21*32*2 = 1344

constexpr float MIN_RATIO = 0.7f, MAX_RATIO = 1.3f;
constexpr float MIN_BIAS  = -4.0f, MAX_BIAS = 4.0f;
constexpr float NEG3LOG2E = -3.0f * 1.4426950408889634f;  // log2-domain scale

__device__ __forceinline__ int compute_o0(float tg, float bb, float ir) {
    const float ocf = (float)LORG + (tg - bb) * ir;
    int o0 = (int)floorf(ocf + 0.5f) - W;
    return max(0, min(LORG - NW, o0));
}

__global__ __launch_bounds__(256) void li_fused(
    const float* __restrict__ x,      // [B, LORG, NCH]
    const float* __restrict__ rmo,    // [NCH]
    const float* __restrict__ bias,   // [NCH]
    float* __restrict__ out)          // [B, LTO, NCH]
{
    // XCD swizzle: 1344 = 8 * 168; consecutive work ids share a t-tile.
    const int h  = blockIdx.x;
    const int wk = (h & 7) * (NBLK / 8) + (h >> 3);
    const int bh = wk & 1;                 // batch half
    const int tn = wk >> 1;                // (t-tile, n)
    const int tt = tn / NCH;
    const int n  = tn - tt * NCH;
    const int t0 = tt * TT;

    const int tid = threadIdx.x;
    const int tl  = tid & 63;              // this thread's t within the tile
    const int wv  = tid >> 6;              // wave id 0..3
    const int b0  = bh * BH;

    __shared__ float xs[4][2][128];        // per-wave double buffer (4 KB)

    const float r  = fminf(fmaxf(rmo[n] + 1.0f, MIN_RATIO), MAX_RATIO);
    const float bb = fminf(fmaxf(bias[n], MIN_BIAS), MAX_BIAS);
    const float ir = 1.0f / r;

    // block-wide window (o0 monotone in t)
    const int lo  = compute_o0((float)(t0 - LTO), bb, ir);
    const int hi  = compute_o0((float)(t0 + TT - 1 - LTO), bb, ir);
    const int len = hi + NW - lo;          // <= ceil(63/0.7)+17 = 107 < 128

    // ---- per-thread weights for its tl (registers; amortized over 4 b) ----
    const float tg = (float)(t0 + tl - LTO);
    const int   o0 = compute_o0(tg, bb, ir);
    const int base = o0 - lo;
    float d = (float)(o0 - LORG) * r + bb - tg;      // d_j = d + j*r
    // analytic max of -3*d_j^2 over j in [0,16]: nearest j to -d/r
    float js = floorf(-d * ir + 0.5f);
    js = fminf(fmaxf(js, 0.0f), 16.0f);
    const float dstar = d + js * r;
    const float m = NEG3LOG2E * dstar * dstar;       // log2-domain max
    float w[NW];
    float s = 0.0f;
    #pragma unroll
    for (int j = 0; j < NW; ++j) {
        const float e = NEG3LOG2E * d * d - m;       // <= 0
        w[j] = exp2f(e);                             // native v_exp_f32
        s += w[j];
        d += r;
    }
    const float inv = 1.0f / s;                      // s >= 1, no NaN

    // staging indices (clamped: lo+127 can run past the tensor for b=31)
    const int i0 = min(tl,      len - 1);
    const int i1 = min(tl + 64, len - 1);

    // ---- prologue: stage batch wv into buffer 0 ----
    {
        const float* col = x + ((size_t)((b0 + wv) * LORG + lo)) * NCH + n;
        const float v0 = col[(size_t)i0 * NCH];
        const float v1 = col[(size_t)i1 * NCH];
        xs[wv][0][tl]      = v0;
        xs[wv][0][tl + 64] = v1;
    }

    // ---- main loop: 4 batches per wave, double-buffered, no barriers ----
    #pragma unroll
    for (int k = 0; k < 4; ++k) {
        const int bl = wv + 4 * k;                   // current batch
        float v0 = 0.0f, v1 = 0.0f;
        if (k < 3) {                                 // issue next batch's loads
            const float* col = x + ((size_t)((b0 + bl + 4) * LORG + lo)) * NCH + n;
            v0 = col[(size_t)i0 * NCH];
            v1 = col[(size_t)i1 * NCH];
        }

        // compute current batch from LDS (lgkmcnt wait auto-inserted)
        float acc = 0.0f;
        #pragma unroll
        for (int j = 0; j < NW; ++j)
            acc = fmaf(w[j], xs[wv][k & 1][base + j], acc);
        out[((size_t)(b0 + bl) * LTO + t0 + tl) * NCH + n] = acc * inv;

        if (k < 3) {                                 // write-late into other half
            xs[wv][(k + 1) & 1][tl]      = v0;
            xs[wv][(k + 1) & 1][tl + 64] = v1;
        }
    }
}

extern "C" void kernel_launch(void* const* d_in, const int* in_sizes, int n_in,
                              void* d_out, int out_size, void* d_ws, size_t ws_size,
                              hipStream_t stream) {
    const float* x    = (const float*)d_in[0];
    const float* rmo  = (const float*)d_in[1];
    const float* bias = (const float*)d_in[2];
    float* out = (float*)d_out;

    li_fused<<<NBLK, 256, 0, stream>>>(x, rmo, bias, out);
}